// Round 2
// baseline (3259.098 us; speedup 1.0000x reference)
//
#include <hip/hip_runtime.h>
#include <cstdint>
#include <cstddef>

// ---------------- problem constants ----------------
constexpr int Bn = 24;
constexpr int Dd = 128;
constexpr int Nn = 2048;
constexpr int Mm = 2048;
constexpr int TT = 64;           // square S tile (x = block-owned axis, y = streamed axis)
constexpr int NIT = Nn / TT;     // 32 iterations over streamed axis
constexpr int VSTR = 68;         // padded LDS row stride for V (16B-aligned rows, low-conflict)
constexpr float INV_KEEP = 1.0f / 0.9f;

// JAX threefry counter mode. Modern JAX (>=0.4.36) defaults to partitionable.
// If bench fails with absmax ~= max|ref| (~450) while structure is right, flip to 0.
#define JAX_THREEFRY_PARTITIONABLE 1

// ---------------- threefry2x32, key = jax.random.key(42) => (0, 42) ----------------
__device__ __forceinline__ uint32_t rotl32(uint32_t x, int r) {
  return (x << r) | (x >> (32 - r));
}

__device__ __forceinline__ void tf2x32(uint32_t& x0, uint32_t& x1) {
  const uint32_t k0 = 0u;
  const uint32_t k1 = 42u;
  const uint32_t k2 = 0x1BD11BDAu ^ 0u ^ 42u;
  x0 += k0; x1 += k1;
#define TFR(r) { x0 += x1; x1 = rotl32(x1, (r)); x1 ^= x0; }
  TFR(13) TFR(15) TFR(26) TFR(6)   x0 += k1; x1 += k2 + 1u;
  TFR(17) TFR(29) TFR(16) TFR(24)  x0 += k2; x1 += k0 + 2u;
  TFR(13) TFR(15) TFR(26) TFR(6)   x0 += k0; x1 += k1 + 3u;
  TFR(17) TFR(29) TFR(16) TFR(24)  x0 += k1; x1 += k2 + 4u;
  TFR(13) TFR(15) TFR(26) TFR(6)   x0 += k2; x1 += k0 + 5u;
#undef TFR
}

// keep iff uniform(bits) < 0.9f  <=>  (bits>>9) < 7549747  (0.9f == 7549747*2^-23 exactly)
__device__ __forceinline__ bool keep_flag(uint32_t j) {
#if JAX_THREEFRY_PARTITIONABLE
  // counts = iota(uint64); hi = 0 (size < 2^32), lo = j; bits = y0 ^ y1
  uint32_t x0 = 0u, x1 = j;
  tf2x32(x0, x1);
  const uint32_t bits = x0 ^ x1;
#else
  // classic: pair (i, i+half); element j<half takes y0, else y1
  const uint32_t half = 12582912u;   // B*4D*N / 2
  const uint32_t i = (j < half) ? j : (j - half);
  uint32_t x0 = i, x1 = i + half;
  tf2x32(x0, x1);
  const uint32_t bits = (j < half) ? x0 : x1;
#endif
  return (bits >> 9) < 7549747u;
}

// ---------------- P0: sc[b,n] = sum_d Wc[b,d] C[b,d,n]; sq[b,m] = sum_d Wq[b,d] Q[b,d,m] ----
__global__ void scq_kernel(const float* __restrict__ Cp, const float* __restrict__ Qp,
                           const float* __restrict__ Wp,
                           float* __restrict__ sc, float* __restrict__ sq) {
  const int z = blockIdx.z;                 // 0 -> sc (C with Wc @ +128), 1 -> sq (Q with Wq @ +0)
  const int b = blockIdx.y;
  const int n = blockIdx.x * 256 + threadIdx.x;
  const float* X = z ? Qp : Cp;
  const float* Wb = Wp + b * 384 + (z ? 0 : 128);
  const float* Xb = X + (size_t)b * Dd * Nn + n;
  float acc = 0.f;
#pragma unroll 8
  for (int d = 0; d < Dd; ++d) acc = fmaf(Wb[d], Xb[(size_t)d * Nn], acc);
  (z ? sq : sc)[b * Nn + n] = acc;
}

// ---------------- shared-memory budget (floats), mirrored host/device ----------------
constexpr int smem_floats(int mode) {
  const int kc = (mode == 4) ? 16 : 32;
  int f = (mode != 1) ? Dd * VSTR : 0;          // Vs
  f += kc * TT;                                  // Ac
  if (mode == 1 || mode == 4) f += kc * TT;      // Bc
  if (mode != 1) f += TT * TT;                   // Es
  if (mode == 1 || mode == 2) f += 64 * 17 + 3 * 64;  // red + sm_l + ss_l + alpha_l
  return f;
}

// ---------------- fused pass kernel ----------------
// MODE 1: x=n, loop m. Stats -> rowL.                         (Ac=wm*C, Bc=Q)
// MODE 2: x=m, loop n. Col stats online; U2=C*S2 -> slot2.    (Ac=wm*Q, V=C) [flash-style]
// MODE 3: x=n, loop m. A=Q*S1^T -> slot1.                     (Ac=wm*C, V=Q) [S1 via rowL]
// MODE 4: x=n, loop m. Bt=U2*S1^T -> slot3.                   (Ac=wm*C, Bc=Q, V=U2) [S1 via rowL]
template<int MODE>
__launch_bounds__(256, 2)
__global__ void pass_kernel(const float* __restrict__ Cp, const float* __restrict__ Qp,
                            const float* __restrict__ Wp, float* outp,
                            float* __restrict__ rowL, float* __restrict__ colL,
                            const float* __restrict__ scp, const float* __restrict__ sqp) {
  constexpr bool HAS_V     = (MODE != 1);
  constexpr bool HAS_STATS = (MODE == 1 || MODE == 2);
  constexpr bool HAS_CONS  = (MODE != 1);
  constexpr bool B_FROM_BC = (MODE == 1 || MODE == 4);
  constexpr int  KCv = (MODE == 4) ? 16 : 32;
  constexpr int  NCH = Dd / KCv;

  extern __shared__ float lds[];
  float* Vs = lds;                                           // [128][VSTR]
  float* Ac = lds + (HAS_V ? Dd * VSTR : 0);                 // [KCv][64]
  float* Bc = Ac + KCv * TT;                                 // [KCv][64] (modes 1,4)
  float* Es = B_FROM_BC ? (Bc + KCv * TT) : (Ac + KCv * TT); // [64][64] (modes 2,3,4)
  float* red  = HAS_CONS ? (Es + TT * TT) : Es;              // [64][17] (modes 1,2)
  float* sm_l = red + 64 * 17;                               // [64] running max per x
  float* ss_l = sm_l + 64;                                   // [64] running sum per x
  float* alpha_l = ss_l + 64;                                // [64] rescale factor (mode 2)

  const int tid = threadIdx.x;
  const int b  = blockIdx.y;
  const int x0 = blockIdx.x * TT;
  const int tx = tid & 15, ty = tid >> 4;   // S-tile map: i->x = x0+tx*4+i, j->y = y0+ty*4+j
  const int txm = tx, tyd = ty;             // consumer map: c->x = x0+txm*4+c, d = r*16+tyd

  const float* Cb = Cp + (size_t)b * Dd * Nn;
  const float* Qb = Qp + (size_t)b * Dd * Nn;
  const float* Wmb = Wp + b * 384 + 256;    // Wm
  float* outb = outp + (size_t)b * 4 * Dd * Nn;

  const float* AcSrc = (MODE == 2) ? Qb : Cb;
  const float* VSrc  = (MODE == 2) ? Cb
                     : (MODE == 3) ? Qb
                     : (outb + 2 * Dd * Nn);                 // MODE 4: U2 from slot2
  const float* axp = ((MODE == 2) ? sqp : scp) + b * Nn;
  const float* byp = ((MODE == 2) ? scp : sqp) + b * Nn;

  float ax[4];
#pragma unroll
  for (int i = 0; i < 4; ++i) ax[i] = axp[x0 + tx * 4 + i];

  float subx[4];
  if constexpr (MODE == 3 || MODE == 4) {
#pragma unroll
    for (int i = 0; i < 4; ++i) subx[i] = rowL[b * Nn + x0 + tx * 4 + i];
  }

  if constexpr (HAS_STATS) {
    if (tid < 64) { sm_l[tid] = -__builtin_inff(); ss_l[tid] = 0.f; alpha_l[tid] = 0.f; }
  }

  float acc[8][4];
  if constexpr (HAS_CONS) {
#pragma unroll
    for (int r = 0; r < 8; ++r)
#pragma unroll
      for (int c = 0; c < 4; ++c) acc[r][c] = 0.f;
  }

#pragma unroll 1
  for (int it = 0; it < NIT; ++it) {
    const int y0 = it * TT;

    float by[4];
#pragma unroll
    for (int j = 0; j < 4; ++j) by[j] = byp[y0 + ty * 4 + j];

    __syncthreads();   // previous iteration's consumers/stats done with Vs/Es/red

    if constexpr (HAS_V) {
#pragma unroll
      for (int q = 0; q < 8; ++q) {
        const int idx = q * 256 + tid;        // coalesced: lanes contiguous
        const int row = idx >> 4;             // 0..127
        const int col = (idx & 15) << 2;      // 0..60
        const float4 v = *(const float4*)(VSrc + (size_t)row * Nn + y0 + col);
        *(float4*)(Vs + row * VSTR + col) = v;
      }
    }

    float Sacc[4][4];
#pragma unroll
    for (int j = 0; j < 4; ++j)
#pragma unroll
      for (int i = 0; i < 4; ++i) Sacc[j][i] = 0.f;

#pragma unroll 1
    for (int cc = 0; cc < NCH; ++cc) {
      const int d0 = cc * KCv;
      if (cc > 0) __syncthreads();            // previous chunk fully consumed
      // stage Ac = wm * AcSrc[:, x-tile]
#pragma unroll
      for (int q = 0; q < KCv / 16; ++q) {
        const int idx = q * 256 + tid;
        const int row = idx >> 4;             // 0..KCv-1
        const int col = (idx & 15) << 2;
        float4 v = *(const float4*)(AcSrc + (size_t)(d0 + row) * Nn + x0 + col);
        const float w = Wmb[d0 + row];
        v.x *= w; v.y *= w; v.z *= w; v.w *= w;
        *(float4*)(Ac + row * TT + col) = v;
      }
      if constexpr (B_FROM_BC) {
#pragma unroll
        for (int q = 0; q < KCv / 16; ++q) {
          const int idx = q * 256 + tid;
          const int row = idx >> 4;
          const int col = (idx & 15) << 2;
          *(float4*)(Bc + row * TT + col) =
              *(const float4*)(Qb + (size_t)(d0 + row) * Nn + y0 + col);
        }
      }
      __syncthreads();
#pragma unroll
      for (int dk = 0; dk < KCv; ++dk) {
        const float4 a4 = *(const float4*)(Ac + dk * TT + tx * 4);
        float4 b4;
        if constexpr (B_FROM_BC) b4 = *(const float4*)(Bc + dk * TT + ty * 4);
        else                     b4 = *(const float4*)(Vs + (d0 + dk) * VSTR + ty * 4);
        const float av[4] = {a4.x, a4.y, a4.z, a4.w};
        const float bv[4] = {b4.x, b4.y, b4.z, b4.w};
#pragma unroll
        for (int j = 0; j < 4; ++j)
#pragma unroll
          for (int i = 0; i < 4; ++i)
            Sacc[j][i] = fmaf(bv[j], av[i], Sacc[j][i]);
      }
    }

    // full logits: S[x, y] = dot + ax[x] + by[y]
#pragma unroll
    for (int j = 0; j < 4; ++j)
#pragma unroll
      for (int i = 0; i < 4; ++i) Sacc[j][i] += ax[i] + by[j];

    if constexpr (HAS_STATS) {
      // online max/sum per x over the streamed axis
#pragma unroll
      for (int i = 0; i < 4; ++i) {
        const float pm = fmaxf(fmaxf(Sacc[0][i], Sacc[1][i]),
                               fmaxf(Sacc[2][i], Sacc[3][i]));
        red[(tx * 4 + i) * 17 + ty] = pm;
      }
      __syncthreads();
      if (tid < 64) {
        const float* rr = red + tid * 17;
        float t = rr[0];
#pragma unroll
        for (int c2 = 1; c2 < 16; ++c2) t = fmaxf(t, rr[c2]);
        const float om = sm_l[tid];
        const float nm = fmaxf(om, t);
        const float al = __expf(om - nm);   // om=-inf first iter -> 0
        ss_l[tid] *= al;
        sm_l[tid] = nm;
        alpha_l[tid] = al;
      }
      __syncthreads();
#pragma unroll
      for (int i = 0; i < 4; ++i) {
        const float mx = sm_l[tx * 4 + i];
        const float ps = __expf(Sacc[0][i] - mx) + __expf(Sacc[1][i] - mx) +
                         __expf(Sacc[2][i] - mx) + __expf(Sacc[3][i] - mx);
        red[(tx * 4 + i) * 17 + ty] = ps;
      }
      __syncthreads();
      if (tid < 64) {
        const float* rr = red + tid * 17;
        float s = rr[0];
#pragma unroll
        for (int c2 = 1; c2 < 16; ++c2) s += rr[c2];
        ss_l[tid] += s;
      }
    }

    if constexpr (HAS_CONS) {
      if constexpr (MODE == 2) {
        // flash rescale of running accumulator by alpha[x]
        float al[4];
#pragma unroll
        for (int c = 0; c < 4; ++c) al[c] = alpha_l[txm * 4 + c];
#pragma unroll
        for (int r = 0; r < 8; ++r)
#pragma unroll
          for (int c = 0; c < 4; ++c) acc[r][c] *= al[c];
      }
      // weights into Es[y_local][x_local]
#pragma unroll
      for (int j = 0; j < 4; ++j) {
        float4 e4;
        if constexpr (MODE == 2) {
          e4.x = __expf(Sacc[j][0] - sm_l[tx * 4 + 0]);
          e4.y = __expf(Sacc[j][1] - sm_l[tx * 4 + 1]);
          e4.z = __expf(Sacc[j][2] - sm_l[tx * 4 + 2]);
          e4.w = __expf(Sacc[j][3] - sm_l[tx * 4 + 3]);
        } else {
          e4.x = __expf(Sacc[j][0] - subx[0]);
          e4.y = __expf(Sacc[j][1] - subx[1]);
          e4.z = __expf(Sacc[j][2] - subx[2]);
          e4.w = __expf(Sacc[j][3] - subx[3]);
        }
        *(float4*)(Es + (ty * 4 + j) * TT + tx * 4) = e4;
      }
      __syncthreads();
      // Out[d, x] += sum_k V[d, y0+k] * Es[k, x]
#pragma unroll 4
      for (int k4 = 0; k4 < TT / 4; ++k4) {
        float ev[4][4];
#pragma unroll
        for (int kk = 0; kk < 4; ++kk) {
          const float4 e4 = *(const float4*)(Es + (k4 * 4 + kk) * TT + txm * 4);
          ev[kk][0] = e4.x; ev[kk][1] = e4.y; ev[kk][2] = e4.z; ev[kk][3] = e4.w;
        }
#pragma unroll
        for (int r = 0; r < 8; ++r) {
          const float4 v4 = *(const float4*)(Vs + (r * 16 + tyd) * VSTR + k4 * 4);
          const float vv[4] = {v4.x, v4.y, v4.z, v4.w};
#pragma unroll
          for (int kk = 0; kk < 4; ++kk)
#pragma unroll
            for (int c = 0; c < 4; ++c)
              acc[r][c] = fmaf(vv[kk], ev[kk][c], acc[r][c]);
        }
      }
    }
  }

  if constexpr (HAS_STATS) {
    if (tid < 64) {
      const float L = sm_l[tid] + logf(ss_l[tid]);
      ((MODE == 1) ? rowL : colL)[b * Nn + x0 + tid] = L;
    }
  }
  if constexpr (HAS_CONS) {
    constexpr int slot = (MODE == 2) ? 2 : (MODE == 3) ? 1 : 3;
    float* Ob = outb + (size_t)slot * Dd * Nn;
    float scl[4] = {1.f, 1.f, 1.f, 1.f};
    if constexpr (MODE == 2) {
#pragma unroll
      for (int c = 0; c < 4; ++c) scl[c] = 1.0f / ss_l[txm * 4 + c];
    }
#pragma unroll
    for (int r = 0; r < 8; ++r) {
      const int d = r * 16 + tyd;
      float4 v;
      v.x = acc[r][0] * scl[0]; v.y = acc[r][1] * scl[1];
      v.z = acc[r][2] * scl[2]; v.w = acc[r][3] * scl[3];
      *(float4*)(Ob + (size_t)d * Nn + x0 + txm * 4) = v;
    }
  }
}

// ---------------- epilogue: concat + exact-JAX dropout, in place ----------------
// slot0=C, slot1=A (raw, from P3), slot2=C*A (overwrites U2), slot3=C*Bt (Bt raw from P4).
// Each thread owns all 4 slot positions of its (b,d,n): race-free in-place transform.
__global__ void epilogue_kernel(const float* __restrict__ Cp, float* __restrict__ outp) {
  const int g = blockIdx.x * 256 + threadIdx.x;   // (b,d,n) flat over B*D*N
  const int b = g >> 18;                          // D*N = 2^18
  const int rem = g & ((1 << 18) - 1);
  const float c = Cp[g];
  const int base = (b << 20) + rem;               // 4*D*N = 2^20
  const float a  = outp[base + (1 << 18)];
  const float bt = outp[base + (3 << 18)];
  const float vals[4] = {c, a, c * a, c * bt};
#pragma unroll
  for (int s = 0; s < 4; ++s) {
    const int j = base + (s << 18);
    outp[j] = keep_flag((uint32_t)j) ? vals[s] * INV_KEEP : 0.0f;
  }
}

// ---------------- launch ----------------
extern "C" void kernel_launch(void* const* d_in, const int* in_sizes, int n_in,
                              void* d_out, int out_size, void* d_ws, size_t ws_size,
                              hipStream_t stream) {
  (void)in_sizes; (void)n_in; (void)out_size; (void)ws_size;
  const float* C = (const float*)d_in[0];
  const float* Q = (const float*)d_in[1];
  const float* W = (const float*)d_in[2];
  float* out = (float*)d_out;
  float* ws = (float*)d_ws;

  float* rowL = ws;                 // [B*N]
  float* colL = ws + Bn * Nn;       // [B*M] (diagnostic only now)
  float* sc   = ws + 2 * Bn * Nn;   // [B*N]
  float* sq   = ws + 3 * Bn * Nn;   // [B*M]

  scq_kernel<<<dim3(Nn / 256, Bn, 2), 256, 0, stream>>>(C, Q, W, sc, sq);

  const dim3 pgrid(NIT, Bn);
  pass_kernel<1><<<pgrid, 256, smem_floats(1) * 4, stream>>>(C, Q, W, out, rowL, colL, sc, sq);
  pass_kernel<2><<<pgrid, 256, smem_floats(2) * 4, stream>>>(C, Q, W, out, rowL, colL, sc, sq);
  pass_kernel<3><<<pgrid, 256, smem_floats(3) * 4, stream>>>(C, Q, W, out, rowL, colL, sc, sq);
  pass_kernel<4><<<pgrid, 256, smem_floats(4) * 4, stream>>>(C, Q, W, out, rowL, colL, sc, sq);

  epilogue_kernel<<<(Bn * Dd * Nn) / 256, 256, 0, stream>>>(C, out);
}

// Round 3
// 1385.596 us; speedup vs baseline: 2.3521x; 2.3521x over previous
//
#include <hip/hip_runtime.h>
#include <cstdint>
#include <cstddef>

// ---------------- problem constants ----------------
constexpr int Bn = 24;
constexpr int Dd = 128;
constexpr int Nn = 2048;
constexpr int DN = Dd * Nn;        // 262144 elements per (b, slot)
constexpr int NIT = Nn / 64;       // 32 streamed tiles
constexpr float INV_KEEP = 1.0f / 0.9f;

// ---------------- vector types ----------------
typedef __attribute__((ext_vector_type(8))) short short8;     // 8 bf16 in 4 VGPRs
typedef __attribute__((ext_vector_type(16))) float floatx16;  // MFMA 32x32 acc

union U8 { uint32_t u[4]; short8 v; };

__device__ __forceinline__ uint32_t f2bf(float f) {
  uint32_t u = __builtin_bit_cast(uint32_t, f);
  return (u + 0x7fffu + ((u >> 16) & 1u)) >> 16;   // RNE
}
__device__ __forceinline__ float bf2f(uint32_t h) {
  return __builtin_bit_cast(float, h << 16);
}

__device__ __forceinline__ floatx16 MFMA(short8 a, short8 b, floatx16 c) {
  return __builtin_amdgcn_mfma_f32_32x32x16_bf16(a, b, c, 0, 0, 0);
}

__device__ __forceinline__ short8 ld_cvt8(const float* p) {
  const float4 a = *(const float4*)p;
  const float4 c = *(const float4*)(p + 4);
  U8 t;
  t.u[0] = f2bf(a.x) | (f2bf(a.y) << 16);
  t.u[1] = f2bf(a.z) | (f2bf(a.w) << 16);
  t.u[2] = f2bf(c.x) | (f2bf(c.y) << 16);
  t.u[3] = f2bf(c.z) | (f2bf(c.w) << 16);
  return t.v;
}

// ---------------- threefry2x32, key = jax.random.key(42) => (0, 42) ----------------
__device__ __forceinline__ uint32_t rotl32(uint32_t x, int r) {
  return (x << r) | (x >> (32 - r));
}
__device__ __forceinline__ void tf2x32(uint32_t& x0, uint32_t& x1) {
  const uint32_t k0 = 0u, k1 = 42u, k2 = 0x1BD11BDAu ^ 0u ^ 42u;
  x0 += k0; x1 += k1;
#define TFR(r) { x0 += x1; x1 = rotl32(x1, (r)); x1 ^= x0; }
  TFR(13) TFR(15) TFR(26) TFR(6)   x0 += k1; x1 += k2 + 1u;
  TFR(17) TFR(29) TFR(16) TFR(24)  x0 += k2; x1 += k0 + 2u;
  TFR(13) TFR(15) TFR(26) TFR(6)   x0 += k0; x1 += k1 + 3u;
  TFR(17) TFR(29) TFR(16) TFR(24)  x0 += k1; x1 += k2 + 4u;
  TFR(13) TFR(15) TFR(26) TFR(6)   x0 += k2; x1 += k0 + 5u;
#undef TFR
}
__device__ __forceinline__ bool keep_flag(uint32_t j) {
  uint32_t x0 = 0u, x1 = j;       // partitionable threefry (verified passing R2)
  tf2x32(x0, x1);
  return ((x0 ^ x1) >> 9) < 7549747u;
}

// ---------------- P0: sc[b,n] = sum_d Wc[b,d] C[b,d,n]; sq = Wq . Q ----------------
__global__ void scq_kernel(const float* __restrict__ Cp, const float* __restrict__ Qp,
                           const float* __restrict__ Wp,
                           float* __restrict__ sc, float* __restrict__ sq) {
  const int z = blockIdx.z;
  const int b = blockIdx.y;
  const int n = blockIdx.x * 256 + threadIdx.x;
  const float* X = z ? Qp : Cp;
  const float* Wb = Wp + b * 384 + (z ? 0 : 128);
  const float* Xb = X + (size_t)b * DN + n;
  float acc = 0.f;
#pragma unroll 8
  for (int d = 0; d < Dd; ++d) acc = fmaf(Wb[d], Xb[(size_t)d * Nn], acc);
  (z ? sq : sc)[b * Nn + n] = acc;
}

// ---------------- split+transpose: X[b][d][n] fp32 -> hi/lo bf16 [b][n][d] -------
// Q -> out slot1 region ; C -> out slot3 region. (hi first DN ushorts, lo next DN)
__global__ __launch_bounds__(256) void split_kernel(const float* __restrict__ Cp,
                                                    const float* __restrict__ Qp,
                                                    float* __restrict__ outp) {
  __shared__ float T[64 * 129];
  const int tid = threadIdx.x;
  const int nt = blockIdx.x, src = blockIdx.y, b = blockIdx.z;
  const float* X = (src ? Qp : Cp) + (size_t)b * DN;
  float* outb = outp + (size_t)b * 4 * DN;
  uint16_t* dsth = (uint16_t*)(outb + (size_t)(src ? 1 : 3) * DN);
  uint16_t* dstl = dsth + DN;
  const int n = nt * 64 + (tid & 63);
  const int dg0 = (tid >> 6) * 32;
#pragma unroll
  for (int r = 0; r < 32; ++r)
    T[(tid & 63) * 129 + dg0 + r] = X[(size_t)(dg0 + r) * Nn + n];
  __syncthreads();
#pragma unroll
  for (int r = 0; r < 4; ++r) {
    const int item = tid + 256 * r;
    const int row = item >> 4;
    const int ch = item & 15;
    const float* tp = T + row * 129 + ch * 8;
    U8 H, L;
#pragma unroll
    for (int e = 0; e < 4; ++e) {
      const float va = tp[2 * e], vb = tp[2 * e + 1];
      const uint32_t ha = f2bf(va), hb = f2bf(vb);
      H.u[e] = ha | (hb << 16);
      L.u[e] = f2bf(va - bf2f(ha)) | (f2bf(vb - bf2f(hb)) << 16);
    }
    const size_t o = (size_t)(nt * 64 + row) * 128 + ch * 8;
    *reinterpret_cast<uint4*>(dsth + o) = *reinterpret_cast<const uint4*>(H.u);
    *reinterpret_cast<uint4*>(dstl + o) = *reinterpret_cast<const uint4*>(L.u);
  }
}

// ---------------- fused flash pass ----------------
// DUAL=false (P2): x=m, stream y=n. S = wmQ.C + sq[x] + sc[y]; S2 weights (softmax
//   over streamed n); U2 = C . S2 -> slot2.
// DUAL=true  (P34): x=n, stream y=m. S = wmC.Q + sc[x] + sq[y]; S1 weights (softmax
//   over streamed m); A = Q . S1 -> slot0 ; Bt = U2 . S1 -> slot3.
// Both flash-online. S-compute uses split bf16 (hi/lo, 3 MFMA products).
template<bool DUAL>
__global__ __launch_bounds__(256, 2) void pass_kernel(
    const float* __restrict__ Cp, const float* __restrict__ Qp,
    const float* __restrict__ Wp, float* __restrict__ outp,
    const float* __restrict__ scp, const float* __restrict__ sqp) {
  extern __shared__ char smem[];
  uint16_t* BsH = (uint16_t*)smem;        // [64][128] bf16 hi, xor-swizzled chunks
  uint16_t* BsL = BsH + 64 * 128;         // [64][128] bf16 lo
  uint16_t* EsS = BsL + 64 * 128;         // [64][64] softmax weights bf16
  float* m_l = (float*)(EsS + 64 * 64);   // [64] running max per x
  float* s_l = m_l + 64;                  // [64] running sum per x
  float* al_l = s_l + 64;                 // [64] rescale alpha per x
  float* pmaxA = al_l + 64;               // [2][64] per-yhalf partial max
  float* psumA = pmaxA + 128;             // [2][64] per-yhalf partial sum

  const int tid = threadIdx.x;
  const int lane = tid & 63;
  const int w = tid >> 6;
  const int xh = w >> 1, yh = w & 1;
  const int lh = lane >> 5, l31 = lane & 31;
  const int b = blockIdx.y;
  const int x0 = blockIdx.x * 64;

  const float* Cb = Cp + (size_t)b * DN;
  const float* Qb = Qp + (size_t)b * DN;
  float* outb = outp + (size_t)b * 4 * DN;
  const float* Wmb = Wp + b * 384 + 256;

  const float* Asrc = DUAL ? Cb : Qb;
  const float* V1 = DUAL ? Qb : Cb;
  const float* V2 = DUAL ? (outb + 2 * DN) : nullptr;
  const uint16_t* BTh = (const uint16_t*)(outb + (size_t)(DUAL ? 1 : 3) * DN);
  const uint16_t* BTl = BTh + DN;
  const float* axp = (DUAL ? scp : sqp) + b * Nn;
  const float* byp = (DUAL ? sqp : scp) + b * Nn;
  float* O1 = DUAL ? outb : (outb + 2 * DN);
  float* O2 = DUAL ? (outb + 3 * DN) : nullptr;

  // ---- A fragments (wm * Asrc) for this wave's 32 x, K=128, split hi/lo ----
  short8 ah[8], al[8];
  {
    const int xg = x0 + xh * 32 + l31;
#pragma unroll
    for (int ks = 0; ks < 8; ++ks) {
      U8 th, tl;
#pragma unroll
      for (int e = 0; e < 4; ++e) {
        const int d0 = ks * 16 + lh * 8 + e * 2;
        const float va = Asrc[(size_t)d0 * Nn + xg] * Wmb[d0];
        const float vb = Asrc[(size_t)(d0 + 1) * Nn + xg] * Wmb[d0 + 1];
        const uint32_t ha = f2bf(va), hb = f2bf(vb);
        th.u[e] = ha | (hb << 16);
        tl.u[e] = f2bf(va - bf2f(ha)) | (f2bf(vb - bf2f(hb)) << 16);
      }
      ah[ks] = th.v; al[ks] = tl.v;
    }
  }

  float axr[16];
#pragma unroll
  for (int r = 0; r < 16; ++r)
    axr[r] = axp[x0 + xh * 32 + (r & 3) + 8 * (r >> 2) + 4 * lh];

  if (tid < 64) { m_l[tid] = -__builtin_inff(); s_l[tid] = 0.f; }

  floatx16 aA0, aA1, aB0, aB1;
#pragma unroll
  for (int r = 0; r < 16; ++r) { aA0[r] = 0.f; aA1[r] = 0.f; }
  if constexpr (DUAL) {
#pragma unroll
    for (int r = 0; r < 16; ++r) { aB0[r] = 0.f; aB1[r] = 0.f; }
  }

  const int yl = yh * 32 + l31;
  const uint16_t* brH = BsH + yl * 128;
  const uint16_t* brL = BsL + yl * 128;

#pragma unroll 1
  for (int it = 0; it < NIT; ++it) {
    const int y0i = it * 64;
    const float by = byp[y0i + yh * 32 + l31];

    // stage B tile (transposed bf16 hi/lo) into LDS, xor-swizzled chunks
    {
      const int yy = tid >> 4, dg = tid & 15;
#pragma unroll
      for (int rr = 0; rr < 4; ++rr) {
        const int y = yy + 16 * rr;
        const size_t gsrc = (size_t)(y0i + y) * 128 + dg * 8;
        const uint4 h = *(const uint4*)(BTh + gsrc);
        const uint4 l = *(const uint4*)(BTl + gsrc);
        const int ch = (dg ^ (y & 15)) * 8;
        *(uint4*)(BsH + y * 128 + ch) = h;
        *(uint4*)(BsL + y * 128 + ch) = l;
      }
    }
    __syncthreads();  // A: staging visible

    // ---- S tile via split-bf16 MFMA ----
    floatx16 S0, S1;
#pragma unroll
    for (int r = 0; r < 16; ++r) { S0[r] = 0.f; S1[r] = 0.f; }
#pragma unroll
    for (int ks = 0; ks < 8; ++ks) {
      const int ch = ((2 * ks + lh) ^ (yl & 15)) * 8;
      const short8 bh = *(const short8*)(brH + ch);
      const short8 bl = *(const short8*)(brL + ch);
      S0 = MFMA(ah[ks], bh, S0);
      S1 = MFMA(ah[ks], bl, S1);
      S0 = MFMA(al[ks], bh, S0);
    }
    float Sv[16];
#pragma unroll
    for (int r = 0; r < 16; ++r) Sv[r] = S0[r] + S1[r] + axr[r] + by;

    // ---- per-x partial max over this wave's 32 y (cols) ----
#pragma unroll
    for (int r = 0; r < 16; ++r) {
      float v = Sv[r];
      v = fmaxf(v, __shfl_xor(v, 1));
      v = fmaxf(v, __shfl_xor(v, 2));
      v = fmaxf(v, __shfl_xor(v, 4));
      v = fmaxf(v, __shfl_xor(v, 8));
      v = fmaxf(v, __shfl_xor(v, 16));
      if (l31 == 0) pmaxA[yh * 64 + xh * 32 + (r & 3) + 8 * (r >> 2) + 4 * lh] = v;
    }
    __syncthreads();  // B
    if (tid < 64) {
      const float p = fmaxf(pmaxA[tid], pmaxA[64 + tid]);
      const float m0 = m_l[tid];
      const float mn = fmaxf(m0, p);
      const float a = __expf(m0 - mn);   // -inf first iter -> 0
      s_l[tid] *= a; m_l[tid] = mn; al_l[tid] = a;
    }
    __syncthreads();  // C
    const float al0 = al_l[l31];
    const float al1 = al_l[32 + l31];
#pragma unroll
    for (int r = 0; r < 16; ++r) {
      const int xl = xh * 32 + (r & 3) + 8 * (r >> 2) + 4 * lh;
      const float e = __expf(Sv[r] - m_l[xl]);
      Sv[r] = e;
      EsS[xl * 64 + (((yl >> 3) ^ (xl & 7)) << 3) + (yl & 7)] = (uint16_t)f2bf(e);
    }
#pragma unroll
    for (int r = 0; r < 16; ++r) {
      float v = Sv[r];
      v += __shfl_xor(v, 1); v += __shfl_xor(v, 2); v += __shfl_xor(v, 4);
      v += __shfl_xor(v, 8); v += __shfl_xor(v, 16);
      if (l31 == 0) psumA[yh * 64 + xh * 32 + (r & 3) + 8 * (r >> 2) + 4 * lh] = v;
    }
    __syncthreads();  // D: Es complete, alpha valid
    if (tid < 64) s_l[tid] += psumA[tid] + psumA[64 + tid];

    // ---- consumers: rescale + accumulate V . Es ----
#pragma unroll
    for (int r = 0; r < 16; ++r) { aA0[r] *= al0; aA1[r] *= al1; }
    if constexpr (DUAL) {
#pragma unroll
      for (int r = 0; r < 16; ++r) { aB0[r] *= al0; aB1[r] *= al1; }
    }
    const int dloc = w * 32 + l31;
    const float* v1r = V1 + (size_t)dloc * Nn + y0i + lh * 8;
    const float* v2r = DUAL ? (V2 + (size_t)dloc * Nn + y0i + lh * 8) : nullptr;
#pragma unroll
    for (int ks = 0; ks < 4; ++ks) {
      const short8 av1 = ld_cvt8(v1r + ks * 16);
      short8 av2;
      if constexpr (DUAL) av2 = ld_cvt8(v2r + ks * 16);
      {
        const int x = l31;
        const int cg = ((2 * ks + lh) ^ (x & 7)) * 8;
        const short8 e = *(const short8*)(EsS + x * 64 + cg);
        aA0 = MFMA(av1, e, aA0);
        if constexpr (DUAL) aB0 = MFMA(av2, e, aB0);
      }
      {
        const int x = 32 + l31;
        const int cg = ((2 * ks + lh) ^ (x & 7)) * 8;
        const short8 e = *(const short8*)(EsS + x * 64 + cg);
        aA1 = MFMA(av1, e, aA1);
        if constexpr (DUAL) aB1 = MFMA(av2, e, aB1);
      }
    }
  }

  __syncthreads();  // final s_l visible to all
  const float inv0 = 1.0f / s_l[l31];
  const float inv1 = 1.0f / s_l[32 + l31];
#pragma unroll
  for (int r = 0; r < 16; ++r) {
    const int d = w * 32 + (r & 3) + 8 * (r >> 2) + 4 * lh;
    float* o1 = O1 + (size_t)d * Nn + x0;
    o1[l31] = aA0[r] * inv0;
    o1[32 + l31] = aA1[r] * inv1;
    if constexpr (DUAL) {
      float* o2 = O2 + (size_t)d * Nn + x0;
      o2[l31] = aB0[r] * inv0;
      o2[32 + l31] = aB1[r] * inv1;
    }
  }
}

// ---------------- epilogue: concat + exact-JAX dropout, in place ----------------
// slot0=A (raw, P34), slot2=U2 (dead), slot3=Bt (raw, P34). Final:
// slot0=drop(C), slot1=drop(A), slot2=drop(C*A), slot3=drop(C*Bt).
__global__ void epilogue_kernel(const float* __restrict__ Cp, float* __restrict__ outp) {
  const int g = blockIdx.x * 256 + threadIdx.x;
  const int b = g >> 18;
  const int rem = g & ((1 << 18) - 1);
  const float c = Cp[g];
  const int base = (b << 20) + rem;
  const float a = outp[base];               // A from slot0
  const float bt = outp[base + (3 << 18)];  // Bt from slot3
  const float vals[4] = {c, a, c * a, c * bt};
#pragma unroll
  for (int s = 0; s < 4; ++s) {
    const int j = base + (s << 18);
    outp[j] = keep_flag((uint32_t)j) ? vals[s] * INV_KEEP : 0.0f;
  }
}

// ---------------- launch ----------------
extern "C" void kernel_launch(void* const* d_in, const int* in_sizes, int n_in,
                              void* d_out, int out_size, void* d_ws, size_t ws_size,
                              hipStream_t stream) {
  (void)in_sizes; (void)n_in; (void)out_size; (void)ws_size;
  const float* C = (const float*)d_in[0];
  const float* Q = (const float*)d_in[1];
  const float* W = (const float*)d_in[2];
  float* out = (float*)d_out;
  float* ws = (float*)d_ws;

  float* sc = ws;             // [B*N]
  float* sq = ws + Bn * Nn;   // [B*M]

  constexpr int SM = (64 * 128 * 2 + 64 * 64) * 2 + (64 * 3 + 128 * 2) * 4;  // 42752 B

  split_kernel<<<dim3(Nn / 64, 2, Bn), 256, 0, stream>>>(C, Q, out);
  scq_kernel<<<dim3(Nn / 256, Bn, 2), 256, 0, stream>>>(C, Q, W, sc, sq);
  pass_kernel<false><<<dim3(Nn / 64, Bn), 256, SM, stream>>>(C, Q, W, out, sc, sq);
  pass_kernel<true><<<dim3(Nn / 64, Bn), 256, SM, stream>>>(C, Q, W, out, sc, sq);
  epilogue_kernel<<<(Bn * DN) / 256, 256, 0, stream>>>(C, out);
}

// Round 4
// 908.748 us; speedup vs baseline: 3.5864x; 1.5247x over previous
//
#include <hip/hip_runtime.h>
#include <cstdint>
#include <cstddef>

// ---------------- problem constants ----------------
constexpr int Bn = 24;
constexpr int Dd = 128;
constexpr int Nn = 2048;
constexpr int DN = Dd * Nn;        // 262144 elements per (b, slot)
constexpr int NIT = Nn / 64;       // 32 streamed tiles
constexpr float INV_KEEP = 1.0f / 0.9f;

// ---------------- vector types ----------------
typedef __attribute__((ext_vector_type(8))) short short8;     // 8 bf16 in 4 VGPRs
typedef __attribute__((ext_vector_type(16))) float floatx16;  // MFMA 32x32 acc

union U8 { uint32_t u[4]; short8 v; };

__device__ __forceinline__ uint32_t f2bf(float f) {
  uint32_t u = __builtin_bit_cast(uint32_t, f);
  return (u + 0x7fffu + ((u >> 16) & 1u)) >> 16;   // RNE
}
__device__ __forceinline__ float bf2f(uint32_t h) {
  return __builtin_bit_cast(float, h << 16);
}

__device__ __forceinline__ floatx16 MFMA(short8 a, short8 b, floatx16 c) {
  return __builtin_amdgcn_mfma_f32_32x32x16_bf16(a, b, c, 0, 0, 0);
}

// pack two fp32 -> two bf16 (truncation) in ONE v_perm_b32
__device__ __forceinline__ uint32_t pack_trunc(float f0, float f1) {
  return __builtin_amdgcn_perm(__builtin_bit_cast(uint32_t, f1),
                               __builtin_bit_cast(uint32_t, f0), 0x07060302u);
}
__device__ __forceinline__ short8 cvt8_trunc(float4 a, float4 b) {
  U8 t;
  t.u[0] = pack_trunc(a.x, a.y);
  t.u[1] = pack_trunc(a.z, a.w);
  t.u[2] = pack_trunc(b.x, b.y);
  t.u[3] = pack_trunc(b.z, b.w);
  return t.v;
}

// ---------------- threefry2x32, key = jax.random.key(42) => (0, 42) ----------------
__device__ __forceinline__ uint32_t rotl32(uint32_t x, int r) {
  return (x << r) | (x >> (32 - r));
}
__device__ __forceinline__ void tf2x32(uint32_t& x0, uint32_t& x1) {
  const uint32_t k0 = 0u, k1 = 42u, k2 = 0x1BD11BDAu ^ 0u ^ 42u;
  x0 += k0; x1 += k1;
#define TFR(r) { x0 += x1; x1 = rotl32(x1, (r)); x1 ^= x0; }
  TFR(13) TFR(15) TFR(26) TFR(6)   x0 += k1; x1 += k2 + 1u;
  TFR(17) TFR(29) TFR(16) TFR(24)  x0 += k2; x1 += k0 + 2u;
  TFR(13) TFR(15) TFR(26) TFR(6)   x0 += k0; x1 += k1 + 3u;
  TFR(17) TFR(29) TFR(16) TFR(24)  x0 += k1; x1 += k2 + 4u;
  TFR(13) TFR(15) TFR(26) TFR(6)   x0 += k2; x1 += k0 + 5u;
#undef TFR
}
__device__ __forceinline__ bool keep_flag(uint32_t j) {
  uint32_t x0 = 0u, x1 = j;       // partitionable threefry (verified passing R2/R3)
  tf2x32(x0, x1);
  return ((x0 ^ x1) >> 9) < 7549747u;
}

// ---------------- P0: sc[b,n] = sum_d Wc[b,d] C[b,d,n]; sq = Wq . Q ----------------
__global__ void scq_kernel(const float* __restrict__ Cp, const float* __restrict__ Qp,
                           const float* __restrict__ Wp,
                           float* __restrict__ sc, float* __restrict__ sq) {
  const int z = blockIdx.z;
  const int b = blockIdx.y;
  const int n = blockIdx.x * 256 + threadIdx.x;
  const float* X = z ? Qp : Cp;
  const float* Wb = Wp + b * 384 + (z ? 0 : 128);
  const float* Xb = X + (size_t)b * DN + n;
  float acc = 0.f;
#pragma unroll 8
  for (int d = 0; d < Dd; ++d) acc = fmaf(Wb[d], Xb[(size_t)d * Nn], acc);
  (z ? sq : sc)[b * Nn + n] = acc;
}

// ---------------- split+transpose: X[b][d][n] fp32 -> hi/lo bf16 [b][n][d] -------
// Q -> out slot1 region ; C -> out slot3 region. (hi first DN ushorts, lo next DN)
__global__ __launch_bounds__(256) void split_kernel(const float* __restrict__ Cp,
                                                    const float* __restrict__ Qp,
                                                    float* __restrict__ outp) {
  __shared__ float T[64 * 129];
  const int tid = threadIdx.x;
  const int nt = blockIdx.x, src = blockIdx.y, b = blockIdx.z;
  const float* X = (src ? Qp : Cp) + (size_t)b * DN;
  float* outb = outp + (size_t)b * 4 * DN;
  uint16_t* dsth = (uint16_t*)(outb + (size_t)(src ? 1 : 3) * DN);
  uint16_t* dstl = dsth + DN;
  const int n = nt * 64 + (tid & 63);
  const int dg0 = (tid >> 6) * 32;
#pragma unroll
  for (int r = 0; r < 32; ++r)
    T[(tid & 63) * 129 + dg0 + r] = X[(size_t)(dg0 + r) * Nn + n];
  __syncthreads();
#pragma unroll
  for (int r = 0; r < 4; ++r) {
    const int item = tid + 256 * r;
    const int row = item >> 4;
    const int ch = item & 15;
    const float* tp = T + row * 129 + ch * 8;
    U8 H, L;
#pragma unroll
    for (int e = 0; e < 4; ++e) {
      const float va = tp[2 * e], vb = tp[2 * e + 1];
      const uint32_t ha = f2bf(va), hb = f2bf(vb);
      H.u[e] = ha | (hb << 16);
      L.u[e] = f2bf(va - bf2f(ha)) | (f2bf(vb - bf2f(hb)) << 16);
    }
    const size_t o = (size_t)(nt * 64 + row) * 128 + ch * 8;
    *reinterpret_cast<uint4*>(dsth + o) = *reinterpret_cast<const uint4*>(H.u);
    *reinterpret_cast<uint4*>(dstl + o) = *reinterpret_cast<const uint4*>(L.u);
  }
}

// ---------------- fused flash pass (S^T layout: softmax axis in-register) --------
// DUAL=false (P2): x=m, stream y=n. S2 weights; U2 = C . S2 -> slot2.
// DUAL=true  (P34): x=n, stream y=m. S1 weights; A = Q . S1 -> slot0 ;
//                   Bt = U2 . S1 -> slot3.
// MFMA computes S^T (streamed y = rows, owned x = cols): per-lane all 16 acc regs
// share one x -> softmax reduction is 15 in-reg ops + 1 shfl_xor(32) + LDS partial.
// Per-x bias cancels in softmax (dropped). m/s/alpha kept in registers.
template<bool DUAL>
__global__ __launch_bounds__(256, 2) void pass_kernel(
    const float* __restrict__ Cp, const float* __restrict__ Qp,
    const float* __restrict__ Wp, float* __restrict__ outp,
    const float* __restrict__ scp, const float* __restrict__ sqp) {
  extern __shared__ char smem[];
  uint16_t* BsH = (uint16_t*)smem;          // [64][128] streamed tile hi (swizzled)
  uint16_t* BsL = BsH + 64 * 128;           // [64][128] lo
  uint16_t* EsS = BsL + 64 * 128;           // [64 x][64 y] weights bf16 (swizzled)
  float* bys   = (float*)(EsS + 64 * 64);   // [2048] streamed-axis bias for this b
  float* pmax  = bys + 2048;                // [2][64] per-yh partial max
  float* al_l  = pmax + 128;                // [64] alpha per x
  float* spart = al_l + 64;                 // [2][64] final sum partials

  const int tid = threadIdx.x;
  const int lane = tid & 63;
  const int w = tid >> 6;
  const int xh = w >> 1, yh = w & 1;
  const int lh = lane >> 5, l31 = lane & 31;
  const int b = blockIdx.y;
  const int x0 = blockIdx.x * 64;

  const float* Cb = Cp + (size_t)b * DN;
  const float* Qb = Qp + (size_t)b * DN;
  float* outb = outp + (size_t)b * 4 * DN;
  const float* Wmb = Wp + b * 384 + 256;

  const float* Asrc = DUAL ? Cb : Qb;        // x-side source (B-operand)
  const float* V1 = DUAL ? Qb : Cb;
  const float* V2 = DUAL ? (outb + 2 * DN) : nullptr;
  const uint16_t* BTh = (const uint16_t*)(outb + (size_t)(DUAL ? 1 : 3) * DN);
  const uint16_t* BTl = BTh + DN;
  const float* byp = (DUAL ? sqp : scp) + b * Nn;
  float* O1 = DUAL ? outb : (outb + 2 * DN);
  float* O2 = DUAL ? (outb + 3 * DN) : nullptr;

  // stage streamed-axis bias into LDS (read 4x float4 per iter later)
  {
    const float4* s4 = (const float4*)byp;
    float4* d4 = (float4*)bys;
    d4[tid] = s4[tid];
    d4[tid + 256] = s4[tid + 256];
  }

  // ---- x-side fragments (wm * Asrc), hi/lo split, resident all 32 iters ----
  short8 xfh[8], xfl[8];
  {
    const int xg = x0 + xh * 32 + l31;
#pragma unroll
    for (int ks = 0; ks < 8; ++ks) {
      U8 th, tl;
#pragma unroll
      for (int e = 0; e < 4; ++e) {
        const int d0 = ks * 16 + lh * 8 + e * 2;
        const float va = Asrc[(size_t)d0 * Nn + xg] * Wmb[d0];
        const float vb = Asrc[(size_t)(d0 + 1) * Nn + xg] * Wmb[d0 + 1];
        const uint32_t ha = f2bf(va), hb = f2bf(vb);
        th.u[e] = ha | (hb << 16);
        tl.u[e] = f2bf(va - bf2f(ha)) | (f2bf(vb - bf2f(hb)) << 16);
      }
      xfh[ks] = th.v; xfl[ks] = tl.v;
    }
  }

  float m_run = -__builtin_inff();
  float s_run = 0.f;

  floatx16 aA0, aA1, aB0, aB1;
#pragma unroll
  for (int r = 0; r < 16; ++r) { aA0[r] = 0.f; aA1[r] = 0.f; }
  if constexpr (DUAL) {
#pragma unroll
    for (int r = 0; r < 16; ++r) { aB0[r] = 0.f; aB1[r] = 0.f; }
  }

  // ---- register prefetch of streamed tile (hi/lo) ----
  const int syy = tid >> 4, sdg = tid & 15;
  uint4 ph[4], pl[4];
#pragma unroll
  for (int rr = 0; rr < 4; ++rr) {
    const size_t gsrc = (size_t)(syy + 16 * rr) * 128 + sdg * 8;
    ph[rr] = *(const uint4*)(BTh + gsrc);
    pl[rr] = *(const uint4*)(BTl + gsrc);
  }

  const int yrow = yh * 32 + l31;
  const uint16_t* brH = BsH + yrow * 128;
  const uint16_t* brL = BsL + yrow * 128;
  const int xl = xh * 32 + l31;

#pragma unroll 1
  for (int it = 0; it < NIT; ++it) {
    const int y0i = it * 64;

    // commit prefetched tile to LDS (prev iter's reads completed before its barriers)
#pragma unroll
    for (int rr = 0; rr < 4; ++rr) {
      const int y = syy + 16 * rr;
      const int ch = (sdg ^ (y & 15)) * 8;
      *(uint4*)(BsH + y * 128 + ch) = ph[rr];
      *(uint4*)(BsL + y * 128 + ch) = pl[rr];
    }
    // prefetch next tile
    {
      const int yn = (it + 1 < NIT) ? (it + 1) * 64 : it * 64;
#pragma unroll
      for (int rr = 0; rr < 4; ++rr) {
        const size_t gsrc = (size_t)(yn + syy + 16 * rr) * 128 + sdg * 8;
        ph[rr] = *(const uint4*)(BTh + gsrc);
        pl[rr] = *(const uint4*)(BTl + gsrc);
      }
    }
    __syncthreads();  // (S) staging visible

    // ---- S^T via split-bf16 MFMA: D[y_row][x_col] ----
    floatx16 S0, S1;
#pragma unroll
    for (int r = 0; r < 16; ++r) { S0[r] = 0.f; S1[r] = 0.f; }
#pragma unroll
    for (int ks = 0; ks < 8; ++ks) {
      const int ch = ((2 * ks + lh) ^ (yrow & 15)) * 8;
      const short8 bh = *(const short8*)(brH + ch);
      const short8 bl = *(const short8*)(brL + ch);
      S0 = MFMA(bh, xfh[ks], S0);
      S1 = MFMA(bl, xfh[ks], S1);
      S0 = MFMA(bh, xfl[ks], S0);
    }

    // logits + streamed-axis bias (per-x bias cancels in softmax)
    float Sv[16];
#pragma unroll
    for (int g = 0; g < 4; ++g) {
      const float4 bv = *(const float4*)(bys + y0i + yh * 32 + 8 * g + 4 * lh);
      Sv[4 * g + 0] = S0[4 * g + 0] + S1[4 * g + 0] + bv.x;
      Sv[4 * g + 1] = S0[4 * g + 1] + S1[4 * g + 1] + bv.y;
      Sv[4 * g + 2] = S0[4 * g + 2] + S1[4 * g + 2] + bv.z;
      Sv[4 * g + 3] = S0[4 * g + 3] + S1[4 * g + 3] + bv.w;
    }

    // ---- per-x max over this wave's 32 y: 15 in-reg + 1 shuffle ----
    float mp = Sv[0];
#pragma unroll
    for (int r = 1; r < 16; ++r) mp = fmaxf(mp, Sv[r]);
    mp = fmaxf(mp, __shfl_xor(mp, 32));
    if (lh == 0) pmax[yh * 64 + xl] = mp;
    __syncthreads();  // (1) pmax visible

    const float pmx = fmaxf(pmax[xl], pmax[64 + xl]);
    const float mn = fmaxf(m_run, pmx);
    const float alpha = __expf(m_run - mn);   // -inf first iter -> 0
    m_run = mn;
    s_run *= alpha;
    if (yh == 0 && lh == 0) al_l[xl] = alpha;

    // ---- issue V loads early (complete by the pre-barrier vmcnt drain) ----
    const int dloc = w * 32 + l31;
    float4 vr1[8], vr2[8];
    {
      const float* v1p = V1 + (size_t)dloc * Nn + y0i + lh * 8;
#pragma unroll
      for (int ks = 0; ks < 4; ++ks) {
        vr1[2 * ks] = *(const float4*)(v1p + ks * 16);
        vr1[2 * ks + 1] = *(const float4*)(v1p + ks * 16 + 4);
      }
      if constexpr (DUAL) {
        const float* v2p = V2 + (size_t)dloc * Nn + y0i + lh * 8;
#pragma unroll
        for (int ks = 0; ks < 4; ++ks) {
          vr2[2 * ks] = *(const float4*)(v2p + ks * 16);
          vr2[2 * ks + 1] = *(const float4*)(v2p + ks * 16 + 4);
        }
      }
    }

    // ---- exp, Es write (b64, swizzled), in-reg sum ----
    float sp = 0.f;
#pragma unroll
    for (int g = 0; g < 4; ++g) {
      const float e0 = __expf(Sv[4 * g + 0] - m_run);
      const float e1 = __expf(Sv[4 * g + 1] - m_run);
      const float e2 = __expf(Sv[4 * g + 2] - m_run);
      const float e3 = __expf(Sv[4 * g + 3] - m_run);
      sp += (e0 + e1) + (e2 + e3);
      uint2 pk;
      pk.x = f2bf(e0) | (f2bf(e1) << 16);
      pk.y = f2bf(e2) | (f2bf(e3) << 16);
      const int c = 4 * yh + g;
      *(uint2*)(EsS + xl * 64 + ((c ^ (xl & 7)) * 8 + 4 * lh)) = pk;
    }
    sp += __shfl_xor(sp, 32);
    s_run += sp;   // per-yh partial; alpha-chain is shared so partials sum at end
    __syncthreads();  // (2) Es + al_l visible

    // ---- consumers: rescale + V . Es ----
    const float a0 = al_l[l31], a1 = al_l[32 + l31];
#pragma unroll
    for (int r = 0; r < 16; ++r) { aA0[r] *= a0; aA1[r] *= a1; }
    if constexpr (DUAL) {
#pragma unroll
      for (int r = 0; r < 16; ++r) { aB0[r] *= a0; aB1[r] *= a1; }
    }
#pragma unroll
    for (int ks = 0; ks < 4; ++ks) {
      const short8 av1 = cvt8_trunc(vr1[2 * ks], vr1[2 * ks + 1]);
      const int sw = ((2 * ks + lh) ^ (l31 & 7)) * 8;
      const short8 e0 = *(const short8*)(EsS + l31 * 64 + sw);
      const short8 e1 = *(const short8*)(EsS + (32 + l31) * 64 + sw);
      aA0 = MFMA(av1, e0, aA0);
      aA1 = MFMA(av1, e1, aA1);
      if constexpr (DUAL) {
        const short8 av2 = cvt8_trunc(vr2[2 * ks], vr2[2 * ks + 1]);
        aB0 = MFMA(av2, e0, aB0);
        aB1 = MFMA(av2, e1, aB1);
      }
    }
  }

  // ---- combine sum partials across yh, normalize, store ----
  if (lh == 0) spart[yh * 64 + xl] = s_run;
  __syncthreads();
  const float inv0 = 1.0f / (spart[l31] + spart[64 + l31]);
  const float inv1 = 1.0f / (spart[32 + l31] + spart[96 + l31]);
#pragma unroll
  for (int r = 0; r < 16; ++r) {
    const int d = w * 32 + (r & 3) + 8 * (r >> 2) + 4 * lh;
    float* o1 = O1 + (size_t)d * Nn + x0;
    o1[l31] = aA0[r] * inv0;
    o1[32 + l31] = aA1[r] * inv1;
    if constexpr (DUAL) {
      float* o2 = O2 + (size_t)d * Nn + x0;
      o2[l31] = aB0[r] * inv0;
      o2[32 + l31] = aB1[r] * inv1;
    }
  }
}

// ---------------- epilogue: concat + exact-JAX dropout, in place ----------------
// slot0=A (raw), slot2=U2 (dead), slot3=Bt (raw). Final: drop(C), drop(A),
// drop(C*A), drop(C*Bt). Thread owns all 4 slots of its (b,d,n): race-free.
__global__ void epilogue_kernel(const float* __restrict__ Cp, float* __restrict__ outp) {
  const int g = blockIdx.x * 256 + threadIdx.x;
  const int b = g >> 18;
  const int rem = g & ((1 << 18) - 1);
  const float c = Cp[g];
  const int base = (b << 20) + rem;
  const float a = outp[base];               // A from slot0
  const float bt = outp[base + (3 << 18)];  // Bt from slot3
  const float vals[4] = {c, a, c * a, c * bt};
#pragma unroll
  for (int s = 0; s < 4; ++s) {
    const int j = base + (s << 18);
    outp[j] = keep_flag((uint32_t)j) ? vals[s] * INV_KEEP : 0.0f;
  }
}

// ---------------- launch ----------------
extern "C" void kernel_launch(void* const* d_in, const int* in_sizes, int n_in,
                              void* d_out, int out_size, void* d_ws, size_t ws_size,
                              hipStream_t stream) {
  (void)in_sizes; (void)n_in; (void)out_size; (void)ws_size;
  const float* C = (const float*)d_in[0];
  const float* Q = (const float*)d_in[1];
  const float* W = (const float*)d_in[2];
  float* out = (float*)d_out;
  float* ws = (float*)d_ws;

  float* sc = ws;             // [B*N]
  float* sq = ws + Bn * Nn;   // [B*M]

  constexpr int SM = (64 * 128 * 2) * 2 + 64 * 64 * 2 + 2048 * 4 +
                     128 * 4 + 64 * 4 + 128 * 4;  // 50432 B

  split_kernel<<<dim3(Nn / 64, 2, Bn), 256, 0, stream>>>(C, Q, out);
  scq_kernel<<<dim3(Nn / 256, Bn, 2), 256, 0, stream>>>(C, Q, W, sc, sq);
  pass_kernel<false><<<dim3(Nn / 64, Bn), 256, SM, stream>>>(C, Q, W, out, sc, sq);
  pass_kernel<true><<<dim3(Nn / 64, Bn), 256, SM, stream>>>(C, Q, W, out, sc, sq);
  epilogue_kernel<<<(Bn * DN) / 256, 256, 0, stream>>>(C, out);
}

// Round 5
// 794.043 us; speedup vs baseline: 4.1044x; 1.1445x over previous
//
#include <hip/hip_runtime.h>
#include <cstdint>
#include <cstddef>

// ---------------- problem constants ----------------
constexpr int Bn = 24;
constexpr int Dd = 128;
constexpr int Nn = 2048;
constexpr int DN = Dd * Nn;        // 262144 elements per (b, slot)
constexpr int NIT = Nn / 64;       // 32 streamed tiles
constexpr float INV_KEEP = 1.0f / 0.9f;

// ---------------- vector types ----------------
typedef __attribute__((ext_vector_type(8))) short short8;     // 8 bf16 in 4 VGPRs
typedef __attribute__((ext_vector_type(16))) float floatx16;  // MFMA 32x32 acc

union U8 { uint32_t u[4]; short8 v; uint4 q; };

__device__ __forceinline__ uint32_t f2bf(float f) {
  uint32_t u = __builtin_bit_cast(uint32_t, f);
  return (u + 0x7fffu + ((u >> 16) & 1u)) >> 16;   // RNE
}
__device__ __forceinline__ float bf2f(uint32_t h) {
  return __builtin_bit_cast(float, h << 16);
}

__device__ __forceinline__ floatx16 MFMA(short8 a, short8 b, floatx16 c) {
  return __builtin_amdgcn_mfma_f32_32x32x16_bf16(a, b, c, 0, 0, 0);
}

// ---------------- threefry2x32, key = jax.random.key(42) => (0, 42) ----------------
__device__ __forceinline__ uint32_t rotl32(uint32_t x, int r) {
  return (x << r) | (x >> (32 - r));
}
__device__ __forceinline__ void tf2x32(uint32_t& x0, uint32_t& x1) {
  const uint32_t k0 = 0u, k1 = 42u, k2 = 0x1BD11BDAu ^ 0u ^ 42u;
  x0 += k0; x1 += k1;
#define TFR(r) { x0 += x1; x1 = rotl32(x1, (r)); x1 ^= x0; }
  TFR(13) TFR(15) TFR(26) TFR(6)   x0 += k1; x1 += k2 + 1u;
  TFR(17) TFR(29) TFR(16) TFR(24)  x0 += k2; x1 += k0 + 2u;
  TFR(13) TFR(15) TFR(26) TFR(6)   x0 += k0; x1 += k1 + 3u;
  TFR(17) TFR(29) TFR(16) TFR(24)  x0 += k1; x1 += k2 + 4u;
  TFR(13) TFR(15) TFR(26) TFR(6)   x0 += k2; x1 += k0 + 5u;
#undef TFR
}
__device__ __forceinline__ bool keep_flag(uint32_t j) {
  uint32_t x0 = 0u, x1 = j;       // partitionable threefry (verified passing R2-R4)
  tf2x32(x0, x1);
  return ((x0 ^ x1) >> 9) < 7549747u;
}

// ---------------- P0: sc[b,n] = sum_d Wc[b,d] C[b,d,n]; sq = Wq . Q ----------------
__global__ void scq_kernel(const float* __restrict__ Cp, const float* __restrict__ Qp,
                           const float* __restrict__ Wp,
                           float* __restrict__ sc, float* __restrict__ sq) {
  const int z = blockIdx.z;
  const int b = blockIdx.y;
  const int n = blockIdx.x * 256 + threadIdx.x;
  const float* X = z ? Qp : Cp;
  const float* Wb = Wp + b * 384 + (z ? 0 : 128);
  const float* Xb = X + (size_t)b * DN + n;
  float acc = 0.f;
#pragma unroll 8
  for (int d = 0; d < Dd; ++d) acc = fmaf(Wb[d], Xb[(size_t)d * Nn], acc);
  (z ? sq : sc)[b * Nn + n] = acc;
}

// ---------------- cvt: C,Q fp32 [d][n] -> bf16 [d][n] into slot0 (lo=C, hi=Q) ----
__global__ __launch_bounds__(256) void cvt_kernel(const float* __restrict__ Cp,
                                                  const float* __restrict__ Qp,
                                                  float* __restrict__ outp) {
  const size_t i = ((size_t)blockIdx.x * 256 + threadIdx.x) * 8;   // over Bn*DN
  const int b = (int)(i >> 18);
  const int rem = (int)(i & (DN - 1));
  uint16_t* d0 = (uint16_t*)(outp + (size_t)b * 4 * DN);
  {
    const float4 a = *(const float4*)(Cp + i);
    const float4 c = *(const float4*)(Cp + i + 4);
    U8 t;
    t.u[0] = f2bf(a.x) | (f2bf(a.y) << 16);
    t.u[1] = f2bf(a.z) | (f2bf(a.w) << 16);
    t.u[2] = f2bf(c.x) | (f2bf(c.y) << 16);
    t.u[3] = f2bf(c.z) | (f2bf(c.w) << 16);
    *(uint4*)(d0 + rem) = t.q;
  }
  {
    const float4 a = *(const float4*)(Qp + i);
    const float4 c = *(const float4*)(Qp + i + 4);
    U8 t;
    t.u[0] = f2bf(a.x) | (f2bf(a.y) << 16);
    t.u[1] = f2bf(a.z) | (f2bf(a.w) << 16);
    t.u[2] = f2bf(c.x) | (f2bf(c.y) << 16);
    t.u[3] = f2bf(c.z) | (f2bf(c.w) << 16);
    *(uint4*)(d0 + DN + rem) = t.q;
  }
}

// ---------------- split+transpose: X[b][d][n] fp32 -> hi/lo bf16 [b][n][d] -------
// Q -> slot1 ; C -> slot3. (hi first DN ushorts, lo next DN)
__global__ __launch_bounds__(256) void split_kernel(const float* __restrict__ Cp,
                                                    const float* __restrict__ Qp,
                                                    float* __restrict__ outp) {
  __shared__ float T[64 * 129];
  const int tid = threadIdx.x;
  const int nt = blockIdx.x, src = blockIdx.y, b = blockIdx.z;
  const float* X = (src ? Qp : Cp) + (size_t)b * DN;
  float* outb = outp + (size_t)b * 4 * DN;
  uint16_t* dsth = (uint16_t*)(outb + (size_t)(src ? 1 : 3) * DN);
  uint16_t* dstl = dsth + DN;
  const int n = nt * 64 + (tid & 63);
  const int dg0 = (tid >> 6) * 32;
#pragma unroll
  for (int r = 0; r < 32; ++r)
    T[(tid & 63) * 129 + dg0 + r] = X[(size_t)(dg0 + r) * Nn + n];
  __syncthreads();
#pragma unroll
  for (int r = 0; r < 4; ++r) {
    const int item = tid + 256 * r;
    const int row = item >> 4;
    const int ch = item & 15;
    const float* tp = T + row * 129 + ch * 8;
    U8 H, L;
#pragma unroll
    for (int e = 0; e < 4; ++e) {
      const float va = tp[2 * e], vb = tp[2 * e + 1];
      const uint32_t ha = f2bf(va), hb = f2bf(vb);
      H.u[e] = ha | (hb << 16);
      L.u[e] = f2bf(va - bf2f(ha)) | (f2bf(vb - bf2f(hb)) << 16);
    }
    const size_t o = (size_t)(nt * 64 + row) * 128 + ch * 8;
    *(uint4*)(dsth + o) = H.q;
    *(uint4*)(dstl + o) = L.q;
  }
}

// ---------------- fused flash pass (S^T layout: softmax axis in-register) --------
// DUAL=false (P2): x=m, stream y=n. S2 weights; U2 = C . S2 -> slot2-lo (bf16).
// DUAL=true  (P34): x=n, stream y=m. S1 weights; A = Q . S1 -> slot3 (fp32);
//                   Bt = U2 . S1 -> slot0-lo (d<64) / slot2-hi (d>=64) (fp32).
// V-operands are pre-converted bf16 [d][n] (slot0: C lo / Q hi; slot2-lo: U2).
template<bool DUAL>
__global__ __launch_bounds__(256, 2) void pass_kernel(
    const float* __restrict__ Cp, const float* __restrict__ Qp,
    const float* __restrict__ Wp, float* __restrict__ outp,
    const float* __restrict__ scp, const float* __restrict__ sqp) {
  extern __shared__ char smem[];
  uint16_t* BsH = (uint16_t*)smem;          // [64][128] streamed tile hi (swizzled)
  uint16_t* BsL = BsH + 64 * 128;           // [64][128] lo
  uint16_t* EsS = BsL + 64 * 128;           // [64 x][64 y] weights bf16 (swizzled)
  float* bys   = (float*)(EsS + 64 * 64);   // [2048] streamed-axis bias for this b
  float* pmax  = bys + 2048;                // [2][64] per-yh partial max
  float* al_l  = pmax + 128;                // [64] alpha per x
  float* spart = al_l + 64;                 // [2][64] final sum partials

  const int tid = threadIdx.x;
  const int lane = tid & 63;
  const int w = tid >> 6;
  const int xh = w >> 1, yh = w & 1;
  const int lh = lane >> 5, l31 = lane & 31;
  const int b = blockIdx.y;
  const int x0 = blockIdx.x * 64;

  const float* Cb = Cp + (size_t)b * DN;
  const float* Qb = Qp + (size_t)b * DN;
  float* outb = outp + (size_t)b * 4 * DN;
  const float* Wmb = Wp + b * 384 + 256;

  const float* Asrc = DUAL ? Cb : Qb;        // x-side source (fp32, hi/lo split here)
  const uint16_t* V1 = (const uint16_t*)outb + (DUAL ? DN : 0);        // Qbf16 / Cbf16
  const uint16_t* V2 = DUAL ? (const uint16_t*)(outb + 2 * DN) : nullptr;  // U2bf16
  const uint16_t* BTh = (const uint16_t*)(outb + (size_t)(DUAL ? 1 : 3) * DN);
  const uint16_t* BTl = BTh + DN;
  const float* byp = (DUAL ? sqp : scp) + b * Nn;

  // stage streamed-axis bias into LDS
  {
    const float4* s4 = (const float4*)byp;
    float4* d4 = (float4*)bys;
    d4[tid] = s4[tid];
    d4[tid + 256] = s4[tid + 256];
  }

  // ---- x-side fragments (wm * Asrc), hi/lo split, resident all 32 iters ----
  short8 xfh[8], xfl[8];
  {
    const int xg = x0 + xh * 32 + l31;
#pragma unroll
    for (int ks = 0; ks < 8; ++ks) {
      U8 th, tl;
#pragma unroll
      for (int e = 0; e < 4; ++e) {
        const int d0 = ks * 16 + lh * 8 + e * 2;
        const float va = Asrc[(size_t)d0 * Nn + xg] * Wmb[d0];
        const float vb = Asrc[(size_t)(d0 + 1) * Nn + xg] * Wmb[d0 + 1];
        const uint32_t ha = f2bf(va), hb = f2bf(vb);
        th.u[e] = ha | (hb << 16);
        tl.u[e] = f2bf(va - bf2f(ha)) | (f2bf(vb - bf2f(hb)) << 16);
      }
      xfh[ks] = th.v; xfl[ks] = tl.v;
    }
  }

  float m_run = -__builtin_inff();
  float s_run = 0.f;

  floatx16 aA0, aA1, aB0, aB1;
#pragma unroll
  for (int r = 0; r < 16; ++r) { aA0[r] = 0.f; aA1[r] = 0.f; }
  if constexpr (DUAL) {
#pragma unroll
    for (int r = 0; r < 16; ++r) { aB0[r] = 0.f; aB1[r] = 0.f; }
  }

  // ---- register prefetch of streamed tile (hi/lo) ----
  const int syy = tid >> 4, sdg = tid & 15;
  uint4 ph[4], pl[4];
#pragma unroll
  for (int rr = 0; rr < 4; ++rr) {
    const size_t gsrc = (size_t)(syy + 16 * rr) * 128 + sdg * 8;
    ph[rr] = *(const uint4*)(BTh + gsrc);
    pl[rr] = *(const uint4*)(BTl + gsrc);
  }

  const int yrow = yh * 32 + l31;
  const uint16_t* brH = BsH + yrow * 128;
  const uint16_t* brL = BsL + yrow * 128;
  const int xl = xh * 32 + l31;
  const int dloc = w * 32 + l31;

#pragma unroll 1
  for (int it = 0; it < NIT; ++it) {
    const int y0i = it * 64;

    // commit prefetched tile to LDS
#pragma unroll
    for (int rr = 0; rr < 4; ++rr) {
      const int y = syy + 16 * rr;
      const int ch = (sdg ^ (y & 15)) * 8;
      *(uint4*)(BsH + y * 128 + ch) = ph[rr];
      *(uint4*)(BsL + y * 128 + ch) = pl[rr];
    }
    // prefetch next tile
    {
      const int yn = (it + 1 < NIT) ? (it + 1) * 64 : it * 64;
#pragma unroll
      for (int rr = 0; rr < 4; ++rr) {
        const size_t gsrc = (size_t)(yn + syy + 16 * rr) * 128 + sdg * 8;
        ph[rr] = *(const uint4*)(BTh + gsrc);
        pl[rr] = *(const uint4*)(BTl + gsrc);
      }
    }
    __syncthreads();  // (S) staging visible

    // ---- S^T via split-bf16 MFMA: D[y_row][x_col] ----
    floatx16 S0, S1;
#pragma unroll
    for (int r = 0; r < 16; ++r) { S0[r] = 0.f; S1[r] = 0.f; }
#pragma unroll
    for (int ks = 0; ks < 8; ++ks) {
      const int ch = ((2 * ks + lh) ^ (yrow & 15)) * 8;
      const short8 bh = *(const short8*)(brH + ch);
      const short8 bl = *(const short8*)(brL + ch);
      S0 = MFMA(bh, xfh[ks], S0);
      S1 = MFMA(bl, xfh[ks], S1);
      S0 = MFMA(bh, xfl[ks], S0);
    }

    // logits + streamed-axis bias (per-x bias cancels in softmax)
    float Sv[16];
#pragma unroll
    for (int g = 0; g < 4; ++g) {
      const float4 bv = *(const float4*)(bys + y0i + yh * 32 + 8 * g + 4 * lh);
      Sv[4 * g + 0] = S0[4 * g + 0] + S1[4 * g + 0] + bv.x;
      Sv[4 * g + 1] = S0[4 * g + 1] + S1[4 * g + 1] + bv.y;
      Sv[4 * g + 2] = S0[4 * g + 2] + S1[4 * g + 2] + bv.z;
      Sv[4 * g + 3] = S0[4 * g + 3] + S1[4 * g + 3] + bv.w;
    }

    // ---- per-x max over this wave's 32 y ----
    float mp = Sv[0];
#pragma unroll
    for (int r = 1; r < 16; ++r) mp = fmaxf(mp, Sv[r]);
    mp = fmaxf(mp, __shfl_xor(mp, 32));
    if (lh == 0) pmax[yh * 64 + xl] = mp;
    __syncthreads();  // (1) pmax visible

    const float pmx = fmaxf(pmax[xl], pmax[64 + xl]);
    const float mn = fmaxf(m_run, pmx);
    const float alpha = __expf(m_run - mn);   // -inf first iter -> 0
    m_run = mn;
    s_run *= alpha;
    if (yh == 0 && lh == 0) al_l[xl] = alpha;

    // ---- issue V fragment loads early (bf16, direct) ----
    short8 vf1[4], vf2[4];
    {
      const uint16_t* v1p = V1 + (size_t)dloc * Nn + y0i + lh * 8;
#pragma unroll
      for (int ks = 0; ks < 4; ++ks)
        vf1[ks] = *(const short8*)(v1p + ks * 16);
      if constexpr (DUAL) {
        const uint16_t* v2p = V2 + (size_t)dloc * Nn + y0i + lh * 8;
#pragma unroll
        for (int ks = 0; ks < 4; ++ks)
          vf2[ks] = *(const short8*)(v2p + ks * 16);
      }
    }

    // ---- exp, Es write (b64, swizzled), in-reg sum ----
    float sp = 0.f;
#pragma unroll
    for (int g = 0; g < 4; ++g) {
      const float e0 = __expf(Sv[4 * g + 0] - m_run);
      const float e1 = __expf(Sv[4 * g + 1] - m_run);
      const float e2 = __expf(Sv[4 * g + 2] - m_run);
      const float e3 = __expf(Sv[4 * g + 3] - m_run);
      sp += (e0 + e1) + (e2 + e3);
      uint2 pk;
      pk.x = f2bf(e0) | (f2bf(e1) << 16);
      pk.y = f2bf(e2) | (f2bf(e3) << 16);
      const int c = 4 * yh + g;
      *(uint2*)(EsS + xl * 64 + ((c ^ (xl & 7)) * 8 + 4 * lh)) = pk;
    }
    sp += __shfl_xor(sp, 32);
    s_run += sp;   // per-yh partial; alpha-chain shared so partials sum at end
    __syncthreads();  // (2) Es + al_l visible

    // ---- consumers: rescale + V . Es ----
    const float a0 = al_l[l31], a1 = al_l[32 + l31];
#pragma unroll
    for (int r = 0; r < 16; ++r) { aA0[r] *= a0; aA1[r] *= a1; }
    if constexpr (DUAL) {
#pragma unroll
      for (int r = 0; r < 16; ++r) { aB0[r] *= a0; aB1[r] *= a1; }
    }
#pragma unroll
    for (int ks = 0; ks < 4; ++ks) {
      const int sw = ((2 * ks + lh) ^ (l31 & 7)) * 8;
      const short8 e0 = *(const short8*)(EsS + l31 * 64 + sw);
      const short8 e1 = *(const short8*)(EsS + (32 + l31) * 64 + sw);
      aA0 = MFMA(vf1[ks], e0, aA0);
      aA1 = MFMA(vf1[ks], e1, aA1);
      if constexpr (DUAL) {
        aB0 = MFMA(vf2[ks], e0, aB0);
        aB1 = MFMA(vf2[ks], e1, aB1);
      }
    }
  }

  // ---- combine sum partials across yh, normalize, store ----
  if (lh == 0) spart[yh * 64 + xl] = s_run;
  __syncthreads();
  const float inv0 = 1.0f / (spart[l31] + spart[64 + l31]);
  const float inv1 = 1.0f / (spart[32 + l31] + spart[96 + l31]);
#pragma unroll
  for (int r = 0; r < 16; ++r) {
    const int d = w * 32 + (r & 3) + 8 * (r >> 2) + 4 * lh;
    if constexpr (DUAL) {
      // A -> slot3 fp32
      float* oa = outb + 3 * DN + (size_t)d * Nn + x0;
      oa[l31] = aA0[r] * inv0;
      oa[32 + l31] = aA1[r] * inv1;
      // Bt -> slot0-lo (d<64) / slot2-hi (d>=64) fp32 (wave-uniform branch)
      float* ob = (d < 64) ? (outb + (size_t)d * Nn + x0)
                           : (outb + 2 * DN + DN / 2 + (size_t)(d - 64) * Nn + x0);
      ob[l31] = aB0[r] * inv0;
      ob[32 + l31] = aB1[r] * inv1;
    } else {
      // U2 -> slot2-lo bf16 [d][n]
      uint16_t* ou = (uint16_t*)(outb + 2 * DN) + (size_t)d * Nn + x0;
      ou[l31] = (uint16_t)f2bf(aA0[r] * inv0);
      ou[32 + l31] = (uint16_t)f2bf(aA1[r] * inv1);
    }
  }
}

// ---------------- epilogue: concat + exact-JAX dropout, in place ----------------
// At entry: slot3=A fp32, Bt fp32 @ slot0-lo (d<64) / slot2-hi (d>=64).
// Final: slot0=drop(C), slot1=drop(A), slot2=drop(C*A), slot3=drop(C*Bt).
// Thread owns all 4 slot positions + its A/Bt reads share its flat index: race-free.
__global__ void epilogue_kernel(const float* __restrict__ Cp, float* __restrict__ outp) {
  const int g = blockIdx.x * 256 + threadIdx.x;
  const int b = g >> 18;
  const int rem = g & ((1 << 18) - 1);
  const int dd = rem >> 11;
  const float c = Cp[g];
  const int base = (b << 20) + rem;
  const float a = outp[base + (3 << 18)];                       // A from slot3
  const float bt = outp[base + ((dd >= 64) ? (2 << 18) : 0)];   // Bt split regions
  const float vals[4] = {c, a, c * a, c * bt};
#pragma unroll
  for (int s = 0; s < 4; ++s) {
    const int j = base + (s << 18);
    outp[j] = keep_flag((uint32_t)j) ? vals[s] * INV_KEEP : 0.0f;
  }
}

// ---------------- launch ----------------
extern "C" void kernel_launch(void* const* d_in, const int* in_sizes, int n_in,
                              void* d_out, int out_size, void* d_ws, size_t ws_size,
                              hipStream_t stream) {
  (void)in_sizes; (void)n_in; (void)out_size; (void)ws_size;
  const float* C = (const float*)d_in[0];
  const float* Q = (const float*)d_in[1];
  const float* W = (const float*)d_in[2];
  float* out = (float*)d_out;
  float* ws = (float*)d_ws;

  float* sc = ws;             // [B*N]
  float* sq = ws + Bn * Nn;   // [B*M]

  constexpr int SM = (64 * 128 * 2) * 2 + 64 * 64 * 2 + 2048 * 4 +
                     128 * 4 + 64 * 4 + 128 * 4;  // 50432 B

  cvt_kernel<<<(Bn * DN) / (256 * 8), 256, 0, stream>>>(C, Q, out);
  split_kernel<<<dim3(Nn / 64, 2, Bn), 256, 0, stream>>>(C, Q, out);
  scq_kernel<<<dim3(Nn / 256, Bn, 2), 256, 0, stream>>>(C, Q, W, sc, sq);
  pass_kernel<false><<<dim3(Nn / 64, Bn), 256, SM, stream>>>(C, Q, W, out, sc, sq);
  pass_kernel<true><<<dim3(Nn / 64, Bn), 256, SM, stream>>>(C, Q, W, out, sc, sq);
  epilogue_kernel<<<(Bn * DN) / 256, 256, 0, stream>>>(C, out);
}